// Round 23
// baseline (532.731 us; speedup 1.0000x reference)
//
#include <hip/hip_runtime.h>
#include <math.h>

constexpr int N = 20000, E = 160000, Bb = 1000;
constexpr int DIN = 7, HID = 64, HEADS = 4, CTXD = 3, EDIM = 5, NL = 4;
constexpr int HH = HEADS * HID; // 256
constexpr int SNB = (N + 255) / 256;  // 79 scan blocks
constexpr int XBLK = N / 16;          // 1250 node-tile blocks

__device__ __forceinline__ float wredsum(float v) {
#pragma unroll
  for (int o = 32; o; o >>= 1) v += __shfl_xor(v, o, 64);
  return v;
}

__device__ __forceinline__ int wredsumi(int v) {
#pragma unroll
  for (int o = 32; o; o >>= 1) v += __shfl_xor(v, o, 64);
  return v;
}

// node init with ctx MLP fused in (3 FMAs per thread, saves a kernel+buffer)
__global__ void k_node_init(const float* __restrict__ x, const float* __restrict__ emb_W,
                            const float* __restrict__ emb_b, const int* __restrict__ role,
                            const float* __restrict__ role_tab, const int* __restrict__ side,
                            const float* __restrict__ side_tab, const float* __restrict__ frame_t,
                            const float* __restrict__ temp_tab, const int* __restrict__ batch,
                            const float* __restrict__ ctx, const float* __restrict__ ctx_W,
                            const float* __restrict__ ctx_b, const float* __restrict__ form_tab,
                            const float* __restrict__ align_tab, const int* __restrict__ form,
                            const int* __restrict__ alig, float* __restrict__ h) {
  int t = blockIdx.x * blockDim.x + threadIdx.x;
  if (t >= N * HID) return;
  int n = t >> 6, j = t & 63;
  float a = emb_b[j];
#pragma unroll
  for (int k = 0; k < DIN; ++k) a += x[n * DIN + k] * emb_W[k * HID + j];
  a = fmaxf(a, 0.f);
  a += role_tab[role[n] * HID + j];
  if (j < 32) a += side_tab[side[n] * 32 + j];
  int ti = (int)(frame_t[0] * 99.f);
  ti = ti < 0 ? 0 : (ti > 99 ? 99 : ti);
  a += temp_tab[ti * HID + j];
  int b = batch[n];
  float c = ctx_b[j];
#pragma unroll
  for (int k = 0; k < CTXD; ++k) c += ctx[b * CTXD + k] * ctx_W[k * HID + j];
  c = fmaxf(c, 0.f);
  c += form_tab[form[b] * HID + j] + align_tab[alig[b] * HID + j];
  h[t] = a + c;
}

__global__ void k_count(const int* __restrict__ ei, int* __restrict__ deg_dst,
                        int* __restrict__ deg_src) {
  int e = blockIdx.x * blockDim.x + threadIdx.x;
  if (e >= E) return;
  atomicAdd(&deg_src[ei[e]], 1);
  atomicAdd(&deg_dst[ei[E + e]], 1);
}

// W2g = W2 @ Wg ; bg2 = bg + b2 @ Wg   (gate directly from pre)
__global__ void k_fuse(const float* __restrict__ W2, const float* __restrict__ Wg,
                       const float* __restrict__ b2, const float* __restrict__ bg,
                       float* __restrict__ W2g, float* __restrict__ bg2) {
  int t = blockIdx.x * 256 + threadIdx.x;
  if (t < HID * HID) {
    int i = t >> 6, j = t & 63;
    float a = 0.f;
#pragma unroll
    for (int k = 0; k < HID; ++k) a += W2[i * HID + k] * Wg[k * HID + j];
    W2g[t] = a;
  }
  if (t < HID) {
    float a = bg[t];
#pragma unroll
    for (int k = 0; k < HID; ++k) a += b2[k] * Wg[k * HID + t];
    bg2[t] = a;
  }
}

// parallel 2-level scan, stage A: per-block sums of both deg arrays
__global__ __launch_bounds__(256) void k_bsum(const int* __restrict__ dA,
                                              const int* __restrict__ dB,
                                              int* __restrict__ bsA, int* __restrict__ bsB) {
  __shared__ int sA[4], sB[4];
  int blk = blockIdx.x, t = threadIdx.x;
  int wid = t >> 6, lane = t & 63;
  int i = blk * 256 + t;
  int vA = (i < N) ? dA[i] : 0;
  int vB = (i < N) ? dB[i] : 0;
  int rA = wredsumi(vA), rB = wredsumi(vB);
  if (lane == 0) {
    sA[wid] = rA;
    sB[wid] = rB;
  }
  __syncthreads();
  if (t == 0) {
    bsA[blk] = sA[0] + sA[1] + sA[2] + sA[3];
    bsB[blk] = sB[0] + sB[1] + sB[2] + sB[3];
  }
}

// stage B: single wave exclusive-scans the block sums in place (nb=79).
// All shfls all-lane-active (chunks padded with 0).
__global__ __launch_bounds__(64) void k_bscan(int* __restrict__ bsA, int* __restrict__ bsB,
                                              int nb) {
  int lane = threadIdx.x;
  for (int arr = 0; arr < 2; ++arr) {
    int* bs = arr ? bsB : bsA;
    int carry = 0;
    for (int base = 0; base < nb; base += 64) {
      int idx = base + lane;
      int v = (idx < nb) ? bs[idx] : 0;
      int s = v;
#pragma unroll
      for (int off = 1; off < 64; off <<= 1) {
        int x = __shfl_up(s, off, 64);
        if (lane >= off) s += x;
      }
      if (idx < nb) bs[idx] = carry + s - v;  // exclusive
      carry += __shfl(s, 63, 64);             // all lanes active: safe
    }
  }
}

// stage C: re-scan each 256-chunk and add the block offset -> row & cur
__global__ __launch_bounds__(256) void k_scan_apply(
    const int* __restrict__ dA, const int* __restrict__ dB, const int* __restrict__ bsA,
    const int* __restrict__ bsB, int* __restrict__ rowA, int* __restrict__ curA,
    int* __restrict__ rowB, int* __restrict__ curB) {
  __shared__ int ws[4];
  int blk = blockIdx.x, t = threadIdx.x;
  int wid = t >> 6, lane = t & 63;
  int i = blk * 256 + t;
  for (int arr = 0; arr < 2; ++arr) {
    const int* deg = arr ? dB : dA;
    const int* bs = arr ? bsB : bsA;
    int* row = arr ? rowB : rowA;
    int* cur = arr ? curB : curA;
    int v = (i < N) ? deg[i] : 0;
    int s = v;
#pragma unroll
    for (int off = 1; off < 64; off <<= 1) {
      int x = __shfl_up(s, off, 64);
      if (lane >= off) s += x;
    }
    if (lane == 63) ws[wid] = s;
    __syncthreads();
    int wexcl = 0;
    for (int k = 0; k < wid; ++k) wexcl += ws[k];  // wid uniform per wave
    int r = bs[blk] + wexcl + s - v;
    if (i < N) {
      row[i] = r;
      cur[i] = r;
    }
    __syncthreads();  // ws reused next pass
  }
}

__global__ void k_scatter(const int* __restrict__ ei, int* __restrict__ cur_dst,
                          int* __restrict__ cur_src, int* __restrict__ eid_dst,
                          int* __restrict__ esrc_dst, int* __restrict__ esrc_srt,
                          int* __restrict__ edst_srt) {
  int e = blockIdx.x * blockDim.x + threadIdx.x;
  if (e >= E) return;
  int s = ei[e], d = ei[E + e];
  int ps = atomicAdd(&cur_src[s], 1);
  esrc_srt[ps] = s;
  edst_srt[ps] = d;
  int pd = atomicAdd(&cur_dst[d], 1);
  eid_dst[pd] = e;
  esrc_dst[pd] = s;
}

__global__ void k_loop_attr(const int* __restrict__ row_dst, const int* __restrict__ deg_dst,
                            const int* __restrict__ eid_dst, const float* __restrict__ ea,
                            float* __restrict__ la) {
  int n = blockIdx.x * blockDim.x + threadIdx.x;
  if (n >= N) return;
  int beg = row_dst[n], cnt = deg_dst[n];
  float s[EDIM] = {0.f, 0.f, 0.f, 0.f, 0.f};
  for (int j = 0; j < cnt; ++j) {
    int e = eid_dst[beg + j];
#pragma unroll
    for (int k = 0; k < EDIM; ++k) s[k] += ea[(size_t)e * EDIM + k];
  }
  float inv = 1.f / fmaxf((float)cnt, 1.f);
#pragma unroll
  for (int k = 0; k < EDIM; ++k) la[n * EDIM + k] = s[k] * inv;
}

// v14 occupancy-split xl/xr GEMM (r22-proven, -75 µs): 64 weights/thread,
// block b<1250 -> xl (Wl), b>=1250 -> xr (Wr); block-uniform branch.
__global__ __launch_bounds__(256) void k_xlxr(const float* __restrict__ h,
                                              const float* __restrict__ Wl,
                                              const float* __restrict__ bl,
                                              const float* __restrict__ Wr,
                                              const float* __restrict__ br,
                                              float* __restrict__ xl, float* __restrict__ xr) {
  constexpr int NB = 16;
  __shared__ float hs[NB][HID];
  int half = (blockIdx.x >= XBLK) ? 1 : 0;  // block-uniform
  int blk = blockIdx.x - half * XBLK;
  const float* W = half ? Wr : Wl;
  const float* bias = half ? br : bl;
  float* outp = half ? xr : xl;
  int n0 = blk * NB;  // grid exact: all rows in-bounds
  for (int idx = threadIdx.x; idx < NB * HID; idx += 256) {
    int r = idx >> 6, c = idx & 63;
    hs[r][c] = h[(n0 + r) * HID + c];
  }
  __syncthreads();
  int t = threadIdx.x;
  float wv[HID];
#pragma unroll
  for (int k = 0; k < HID; ++k) wv[k] = W[k * HH + t];
  float bv = bias[t];
#pragma unroll 4
  for (int r = 0; r < NB; ++r) {
    float acc = bv;
#pragma unroll
    for (int k = 0; k < HID; ++k) acc += hs[r][k] * wv[k];
    outp[(size_t)(n0 + r) * HH + t] = acc;
  }
}

// per-node GATv2, fused ONLINE softmax, 2-STAGE PREFETCH: indices two
// iterations ahead, VALUES (xl4 + 5 ea floats) one iteration ahead — value
// loads for j+1 issue during j's compute, hiding the L2 chain. Identical
// arithmetic & shfl structure to r16/r22 (safety invariant: no data-
// dependent shfl; within-group o<16 reduces + all-lane merges only; all
// prefetch addresses valid dummies la[n]/xl[n]).
__global__ __launch_bounds__(256) void k_gat(
    const float* __restrict__ xl, const float* __restrict__ xr, const float* __restrict__ ea,
    const float* __restrict__ la, const int* __restrict__ row_dst,
    const int* __restrict__ deg_dst, const int* __restrict__ eid_dst,
    const int* __restrict__ esrc_dst, const float* __restrict__ We,
    const float* __restrict__ att, const float* __restrict__ biasL,
    const float* __restrict__ lng, const float* __restrict__ lnb, float* __restrict__ h) {
  __shared__ float heads[HEADS][HID];
  int n = blockIdx.x;
  int w = threadIdx.x >> 6, lane = threadIdx.x & 63;
  int g = lane >> 4, q = lane & 15, c4 = q * 4;
  const float* xlbase = xl + (size_t)w * HID + c4;
  const float* lan = la + (size_t)n * EDIM;
  float4 xr4 = *(const float4*)(xr + (size_t)n * HH + w * HID + c4);
  float4 att4 = *(const float4*)(att + w * HID + c4);
  float4 we4[EDIM];
#pragma unroll
  for (int k = 0; k < EDIM; ++k) we4[k] = *(const float4*)(We + k * HH + w * HID + c4);
  int beg = row_dst[n], cnt = deg_dst[n];
  int tot = cnt + 1;  // + self loop (idx 0)
  float mg = -INFINITY, sg = 0.f;
  float ax = 0.f, ay = 0.f, az = 0.f, aw2 = 0.f;
  // indices for iter 0 (group-uniform, always-valid addresses)
  int srcnB;
  const float* eapB;
  if (g == 0 || g >= tot) {
    srcnB = n;
    eapB = lan;
  } else {
    int pos = beg + g - 1;
    srcnB = esrc_dst[pos];
    eapB = ea + (size_t)eid_dst[pos] * EDIM;
  }
  // values for iter 0
  float4 xl4_p = *(const float4*)(xlbase + (size_t)srcnB * HH);
  float e0p = eapB[0], e1p = eapB[1], e2p = eapB[2], e3p = eapB[3], e4p = eapB[4];
  // indices for iter 1
  {
    int idx1 = 4 + g;
    if (idx1 >= tot) {
      srcnB = n;
      eapB = lan;
    } else {
      int pos = beg + idx1 - 1;
      srcnB = esrc_dst[pos];
      eapB = ea + (size_t)eid_dst[pos] * EDIM;
    }
  }
  for (int j = 0; j * 4 < tot; ++j) {
    int idx = j * 4 + g;  // uniform within each 16-lane group
    // take current values
    float4 xl4 = xl4_p;
    float e0 = e0p, e1 = e1p, e2 = e2p, e3 = e3p, e4 = e4p;
    // issue value loads for j+1 (indices already in regs)
    xl4_p = *(const float4*)(xlbase + (size_t)srcnB * HH);
    e0p = eapB[0]; e1p = eapB[1]; e2p = eapB[2]; e3p = eapB[3]; e4p = eapB[4];
    // issue index loads for j+2
    int idx2 = idx + 8;
    if (idx2 >= tot) {
      srcnB = n;
      eapB = lan;
    } else {
      int pos = beg + idx2 - 1;
      srcnB = esrc_dst[pos];
      eapB = ea + (size_t)eid_dst[pos] * EDIM;
    }
    if (idx < tot) {  // group-uniform predicate
      float epx = e0 * we4[0].x + e1 * we4[1].x + e2 * we4[2].x + e3 * we4[3].x + e4 * we4[4].x;
      float epy = e0 * we4[0].y + e1 * we4[1].y + e2 * we4[2].y + e3 * we4[3].y + e4 * we4[4].y;
      float epz = e0 * we4[0].z + e1 * we4[1].z + e2 * we4[2].z + e3 * we4[3].z + e4 * we4[4].z;
      float epw = e0 * we4[0].w + e1 * we4[1].w + e2 * we4[2].w + e3 * we4[3].w + e4 * we4[4].w;
      float v0 = xl4.x + xr4.x + epx;
      float v1 = xl4.y + xr4.y + epy;
      float v2 = xl4.z + xr4.z + epz;
      float v3 = xl4.w + xr4.w + epw;
      v0 = v0 > 0.f ? v0 : 0.2f * v0;
      v1 = v1 > 0.f ? v1 : 0.2f * v1;
      v2 = v2 > 0.f ? v2 : 0.2f * v2;
      v3 = v3 > 0.f ? v3 : 0.2f * v3;
      float dot = v0 * att4.x + v1 * att4.y + v2 * att4.z + v3 * att4.w;
      // within-group reduce: o<16 stays inside the fully-active group
#pragma unroll
      for (int o = 1; o < 16; o <<= 1) dot += __shfl_xor(dot, o, 64);
      // per-group online softmax update (register-only)
      float nm = fmaxf(mg, dot);
      float sc = __expf(mg - nm);  // first iter: exp(-inf)=0
      float pp = __expf(dot - nm);
      sg = sg * sc + pp;
      ax = ax * sc + pp * xl4.x;
      ay = ay * sc + pp * xl4.y;
      az = az * sc + pp * xl4.z;
      aw2 = aw2 * sc + pp * xl4.w;
      mg = nm;
    }
  }
  // merge the 4 group states (all 64 lanes active; pure register shfls)
  float mm = fmaxf(mg, __shfl_xor(mg, 16, 64));
  mm = fmaxf(mm, __shfl_xor(mm, 32, 64));
  float scale = __expf(mg - mm);  // never-active groups: exp(-inf)=0
  float st = sg * scale;
  st += __shfl_xor(st, 16, 64);
  st += __shfl_xor(st, 32, 64);
  ax *= scale; ax += __shfl_xor(ax, 16, 64); ax += __shfl_xor(ax, 32, 64);
  ay *= scale; ay += __shfl_xor(ay, 16, 64); ay += __shfl_xor(ay, 32, 64);
  az *= scale; az += __shfl_xor(az, 16, 64); az += __shfl_xor(az, 32, 64);
  aw2 *= scale; aw2 += __shfl_xor(aw2, 16, 64); aw2 += __shfl_xor(aw2, 32, 64);
  float inv = 1.f / (st + 1e-16f);
  if (g == 0) {
    heads[w][c4 + 0] = ax * inv;
    heads[w][c4 + 1] = ay * inv;
    heads[w][c4 + 2] = az * inv;
    heads[w][c4 + 3] = aw2 * inv;
  }
  __syncthreads();
  if (w == 0) {
    float hv = (heads[0][lane] + heads[1][lane] + heads[2][lane] + heads[3][lane]) * 0.25f +
               biasL[lane];
    hv = fmaxf(hv, 0.f);
    float v = hv + h[n * HID + lane];
    float mu = wredsum(v) * (1.f / 64.f);
    float d = v - mu;
    float var = wredsum(d * d) * (1.f / 64.f);
    h[n * HID + lane] = d * rsqrtf(var + 1e-5f) * lng[lane] + lnb[lane];
  }
}

// v15: k_uv occupancy-split (same transform as k_xlxr v14): block b<1250
// computes u (W1 top half + b1), b>=1250 computes v (W1 bottom half, no
// bias). 64 weights/thread, block-uniform branch, grid exact (N/16=1250).
__global__ __launch_bounds__(256) void k_uv(const float* __restrict__ h,
                                            const float* __restrict__ W1,
                                            const float* __restrict__ b1,
                                            float* __restrict__ u, float* __restrict__ v) {
  constexpr int NB = 16;
  __shared__ float hs[NB][HID];
  int half = (blockIdx.x >= XBLK) ? 1 : 0;  // block-uniform
  int blk = blockIdx.x - half * XBLK;
  int n0 = blk * NB;
  for (int idx = threadIdx.x; idx < NB * HID; idx += 256) {
    int r = idx >> 6, c = idx & 63;
    hs[r][c] = h[(n0 + r) * HID + c];
  }
  __syncthreads();
  int j = threadIdx.x & 63, q = threadIdx.x >> 6;
  const float* W = W1 + (half ? (size_t)HID * HID : 0);  // wb[k]=W1[(HID+k)*HID+j]
  float* outp = half ? v : u;
  float wv[HID];
#pragma unroll
  for (int k = 0; k < HID; ++k) wv[k] = W[k * HID + j];
  float bv = half ? 0.f : b1[j];
  for (int r = q; r < NB; r += 4) {
    float acc = bv;
#pragma unroll
    for (int k = 0; k < HID; ++k) acc += hs[r][k] * wv[k];
    outp[(size_t)(n0 + r) * HID + j] = acc;
  }
}

// r16-exact k_edge (best of 5 attempts at 67 µs): 4 waves/block, 32
// edges/wave. lane = output feature; W2/W2g columns per lane (compiler
// keeps them L1-hot; residency-forcing variants all regressed).
// Activations via wave-uniform broadcast ds_read_b128; coalesced stores.
__global__ __launch_bounds__(256) void k_edge(const float* __restrict__ u,
                                              const float* __restrict__ v,
                                              const int* __restrict__ esrc_srt,
                                              const int* __restrict__ edst_srt,
                                              const float* __restrict__ W2,
                                              const float* __restrict__ b2,
                                              const float* __restrict__ W2g,
                                              const float* __restrict__ bg2,
                                              float* __restrict__ gated) {
  __shared__ float T[4][32 * 68];
  int w = threadIdx.x >> 6, lane = threadIdx.x & 63;
  float* Tw = T[w];
  int p0 = blockIdx.x * 128 + w * 32;  // E % 128 == 0
  float w2c[HID], wgc[HID];
#pragma unroll
  for (int k = 0; k < HID; ++k) {
    w2c[k] = W2[k * HID + lane];   // coalesced: lane j gets column j
    wgc[k] = W2g[k * HID + lane];
  }
  float b2v = b2[lane], bgv = bg2[lane];
  int sv = esrc_srt[p0 + (lane & 31)];
  int dv = edst_srt[p0 + (lane & 31)];
  // phase A: coalesced activation-row gathers into this wave's LDS tile
  for (int i = 0; i < 32; ++i) {
    int si = __shfl(sv, i, 64), di = __shfl(dv, i, 64);
    Tw[i * 68 + lane] = fmaxf(u[(size_t)si * HID + lane] + v[(size_t)di * HID + lane], 0.f);
  }
  __syncthreads();
  // phase B: per edge, uniform-broadcast LDS reads feed dual register GEMV
#pragma unroll 2
  for (int i = 0; i < 32; ++i) {
    float it0 = b2v, gt0 = bgv, it1 = 0.f, gt1 = 0.f;
#pragma unroll
    for (int k4 = 0; k4 < 16; ++k4) {
      float4 a = *(const float4*)&Tw[i * 68 + k4 * 4];  // uniform addr -> broadcast
      it0 += a.x * w2c[k4 * 4 + 0];
      gt0 += a.x * wgc[k4 * 4 + 0];
      it1 += a.y * w2c[k4 * 4 + 1];
      gt1 += a.y * wgc[k4 * 4 + 1];
      it0 += a.z * w2c[k4 * 4 + 2];
      gt0 += a.z * wgc[k4 * 4 + 2];
      it1 += a.w * w2c[k4 * 4 + 3];
      gt1 += a.w * wgc[k4 * 4 + 3];
    }
    float it = it0 + it1, gt = gt0 + gt1;
    gated[(size_t)(p0 + i) * HID + lane] = it / (1.f + __expf(-gt));
  }
}

__global__ void k_pool(const float* __restrict__ h, const float* __restrict__ gated,
                       const int* __restrict__ row_src, const int* __restrict__ deg_src,
                       const float* __restrict__ g, const float* __restrict__ b,
                       float* __restrict__ out) {
  int n = blockIdx.x * 4 + (threadIdx.x >> 6);
  int lane = threadIdx.x & 63;
  if (n >= N) return;
  int beg = row_src[n], cnt = deg_src[n];
  float acc = 0.f;
  for (int i = 0; i < cnt; ++i) acc += gated[(size_t)(beg + i) * HID + lane];
  float v = h[n * HID + lane] + acc / fmaxf((float)cnt, 1.f);
  float mu = wredsum(v) * (1.f / 64.f);
  float d = v - mu;
  float var = wredsum(d * d) * (1.f / 64.f);
  out[n * HID + lane] = d * rsqrtf(var + 1e-5f) * g[lane] + b[lane];
}

extern "C" void kernel_launch(void* const* d_in, const int* in_sizes, int n_in, void* d_out,
                              int out_size, void* d_ws, size_t ws_size, hipStream_t stream) {
  const float* x = (const float*)d_in[0];
  const int* ei = (const int*)d_in[1];
  const float* eattr = (const float*)d_in[2];
  const float* ctx = (const float*)d_in[3];
  const int* batch = (const int*)d_in[4];
  const int* role = (const int*)d_in[5];
  const int* side = (const int*)d_in[6];
  const int* form = (const int*)d_in[7];
  const int* alig = (const int*)d_in[8];
  const float* frame_t = (const float*)d_in[9];
  const float* emb_W = (const float*)d_in[10];
  const float* emb_b = (const float*)d_in[11];
  const float* role_tab = (const float*)d_in[12];
  const float* side_tab = (const float*)d_in[13];
  const float* ctx_W = (const float*)d_in[14];
  const float* ctx_b = (const float*)d_in[15];
  const float* form_tab = (const float*)d_in[16];
  const float* align_tab = (const float*)d_in[17];
  const float* temp_tab = (const float*)d_in[18];
  const float* gat_Wl = (const float*)d_in[19];
  const float* gat_bl = (const float*)d_in[20];
  const float* gat_Wr = (const float*)d_in[21];
  const float* gat_br = (const float*)d_in[22];
  const float* gat_We = (const float*)d_in[23];
  const float* gat_att = (const float*)d_in[24];
  const float* gat_bias = (const float*)d_in[25];
  const float* ln_g = (const float*)d_in[26];
  const float* ln_b = (const float*)d_in[27];
  const float* sp_W1 = (const float*)d_in[28];
  const float* sp_b1 = (const float*)d_in[29];
  const float* sp_W2 = (const float*)d_in[30];
  const float* sp_b2 = (const float*)d_in[31];
  const float* sp_Wg = (const float*)d_in[32];
  const float* sp_bg = (const float*)d_in[33];
  const float* fn_g = (const float*)d_in[34];
  const float* fn_b = (const float*)d_in[35];
  float* out = (float*)d_out;

  char* wp = (char*)d_ws;
  auto alloc = [&](size_t bytes) {
    void* p = (void*)wp;
    wp += (bytes + 255) & ~(size_t)255;
    return p;
  };
  float* h = (float*)alloc((size_t)N * HID * 4);
  float* xl = (float*)alloc((size_t)N * HH * 4);  // + xr below = 41 MB, reused as gated[E][64]
  float* xr = (float*)alloc((size_t)N * HH * 4);
  float* la = (float*)alloc((size_t)N * EDIM * 4);
  float* u = (float*)alloc((size_t)N * HID * 4);
  float* v = (float*)alloc((size_t)N * HID * 4);
  float* W2g = (float*)alloc((size_t)HID * HID * 4);
  float* bg2 = (float*)alloc((size_t)HID * 4);
  int* deg_dst = (int*)alloc((size_t)N * 4);
  int* deg_src = (int*)alloc((size_t)N * 4);
  int* row_dst = (int*)alloc((size_t)N * 4);
  int* row_src = (int*)alloc((size_t)N * 4);
  int* cur_dst = (int*)alloc((size_t)N * 4);
  int* cur_src = (int*)alloc((size_t)N * 4);
  int* eid_dst = (int*)alloc((size_t)E * 4);
  int* esrc_dst = (int*)alloc((size_t)E * 4);
  int* esrc_srt = (int*)alloc((size_t)E * 4);
  int* edst_srt = (int*)alloc((size_t)E * 4);
  int* bsA = (int*)alloc((size_t)SNB * 4);
  int* bsB = (int*)alloc((size_t)SNB * 4);
  float* gated = xl;  // [E][64] = 41 MB, spans xl+xr (both dead by then)

  hipMemsetAsync(deg_dst, 0, (size_t)N * 4, stream);
  hipMemsetAsync(deg_src, 0, (size_t)N * 4, stream);

  k_node_init<<<(N * HID + 255) / 256, 256, 0, stream>>>(
      x, emb_W, emb_b, role, role_tab, side, side_tab, frame_t, temp_tab, batch, ctx, ctx_W,
      ctx_b, form_tab, align_tab, form, alig, h);
  k_count<<<(E + 255) / 256, 256, 0, stream>>>(ei, deg_dst, deg_src);
  k_fuse<<<16, 256, 0, stream>>>(sp_W2, sp_Wg, sp_b2, sp_bg, W2g, bg2);
  k_bsum<<<SNB, 256, 0, stream>>>(deg_dst, deg_src, bsA, bsB);
  k_bscan<<<1, 64, 0, stream>>>(bsA, bsB, SNB);
  k_scan_apply<<<SNB, 256, 0, stream>>>(deg_dst, deg_src, bsA, bsB, row_dst, cur_dst, row_src,
                                        cur_src);
  k_scatter<<<(E + 255) / 256, 256, 0, stream>>>(ei, cur_dst, cur_src, eid_dst, esrc_dst,
                                                 esrc_srt, edst_srt);
  k_loop_attr<<<(N + 255) / 256, 256, 0, stream>>>(row_dst, deg_dst, eid_dst, eattr, la);

  for (int i = 0; i < NL; ++i) {
    k_xlxr<<<2 * XBLK, 256, 0, stream>>>(h, gat_Wl + (size_t)i * HID * HH, gat_bl + i * HH,
                                         gat_Wr + (size_t)i * HID * HH, gat_br + i * HH, xl, xr);
    k_gat<<<N, 256, 0, stream>>>(xl, xr, eattr, la, row_dst, deg_dst, eid_dst, esrc_dst,
                                 gat_We + (size_t)i * EDIM * HH, gat_att + i * HH,
                                 gat_bias + i * HID, ln_g + i * HID, ln_b + i * HID, h);
  }

  k_uv<<<2 * XBLK, 256, 0, stream>>>(h, sp_W1, sp_b1, u, v);
  k_edge<<<E / 128, 256, 0, stream>>>(u, v, esrc_srt, edst_srt, sp_W2, sp_b2, W2g, bg2, gated);
  k_pool<<<(N + 3) / 4, 256, 0, stream>>>(h, gated, row_src, deg_src, fn_g, fn_b, out);
}

// Round 24
// 528.342 us; speedup vs baseline: 1.0083x; 1.0083x over previous
//
#include <hip/hip_runtime.h>
#include <math.h>

constexpr int N = 20000, E = 160000, Bb = 1000;
constexpr int DIN = 7, HID = 64, HEADS = 4, CTXD = 3, EDIM = 5, NL = 4;
constexpr int HH = HEADS * HID; // 256
constexpr int SNB = (N + 255) / 256;  // 79 scan blocks
constexpr int XBLK = N / 16;          // 1250 node-tile blocks

__device__ __forceinline__ float wredsum(float v) {
#pragma unroll
  for (int o = 32; o; o >>= 1) v += __shfl_xor(v, o, 64);
  return v;
}

__device__ __forceinline__ int wredsumi(int v) {
#pragma unroll
  for (int o = 32; o; o >>= 1) v += __shfl_xor(v, o, 64);
  return v;
}

// node init with ctx MLP fused in (3 FMAs per thread, saves a kernel+buffer)
__global__ void k_node_init(const float* __restrict__ x, const float* __restrict__ emb_W,
                            const float* __restrict__ emb_b, const int* __restrict__ role,
                            const float* __restrict__ role_tab, const int* __restrict__ side,
                            const float* __restrict__ side_tab, const float* __restrict__ frame_t,
                            const float* __restrict__ temp_tab, const int* __restrict__ batch,
                            const float* __restrict__ ctx, const float* __restrict__ ctx_W,
                            const float* __restrict__ ctx_b, const float* __restrict__ form_tab,
                            const float* __restrict__ align_tab, const int* __restrict__ form,
                            const int* __restrict__ alig, float* __restrict__ h) {
  int t = blockIdx.x * blockDim.x + threadIdx.x;
  if (t >= N * HID) return;
  int n = t >> 6, j = t & 63;
  float a = emb_b[j];
#pragma unroll
  for (int k = 0; k < DIN; ++k) a += x[n * DIN + k] * emb_W[k * HID + j];
  a = fmaxf(a, 0.f);
  a += role_tab[role[n] * HID + j];
  if (j < 32) a += side_tab[side[n] * 32 + j];
  int ti = (int)(frame_t[0] * 99.f);
  ti = ti < 0 ? 0 : (ti > 99 ? 99 : ti);
  a += temp_tab[ti * HID + j];
  int b = batch[n];
  float c = ctx_b[j];
#pragma unroll
  for (int k = 0; k < CTXD; ++k) c += ctx[b * CTXD + k] * ctx_W[k * HID + j];
  c = fmaxf(c, 0.f);
  c += form_tab[form[b] * HID + j] + align_tab[alig[b] * HID + j];
  h[t] = a + c;
}

__global__ void k_count(const int* __restrict__ ei, int* __restrict__ deg_dst,
                        int* __restrict__ deg_src) {
  int e = blockIdx.x * blockDim.x + threadIdx.x;
  if (e >= E) return;
  atomicAdd(&deg_src[ei[e]], 1);
  atomicAdd(&deg_dst[ei[E + e]], 1);
}

// W2g = W2 @ Wg ; bg2 = bg + b2 @ Wg   (gate directly from pre)
__global__ void k_fuse(const float* __restrict__ W2, const float* __restrict__ Wg,
                       const float* __restrict__ b2, const float* __restrict__ bg,
                       float* __restrict__ W2g, float* __restrict__ bg2) {
  int t = blockIdx.x * 256 + threadIdx.x;
  if (t < HID * HID) {
    int i = t >> 6, j = t & 63;
    float a = 0.f;
#pragma unroll
    for (int k = 0; k < HID; ++k) a += W2[i * HID + k] * Wg[k * HID + j];
    W2g[t] = a;
  }
  if (t < HID) {
    float a = bg[t];
#pragma unroll
    for (int k = 0; k < HID; ++k) a += b2[k] * Wg[k * HID + t];
    bg2[t] = a;
  }
}

// parallel 2-level scan, stage A: per-block sums of both deg arrays
__global__ __launch_bounds__(256) void k_bsum(const int* __restrict__ dA,
                                              const int* __restrict__ dB,
                                              int* __restrict__ bsA, int* __restrict__ bsB) {
  __shared__ int sA[4], sB[4];
  int blk = blockIdx.x, t = threadIdx.x;
  int wid = t >> 6, lane = t & 63;
  int i = blk * 256 + t;
  int vA = (i < N) ? dA[i] : 0;
  int vB = (i < N) ? dB[i] : 0;
  int rA = wredsumi(vA), rB = wredsumi(vB);
  if (lane == 0) {
    sA[wid] = rA;
    sB[wid] = rB;
  }
  __syncthreads();
  if (t == 0) {
    bsA[blk] = sA[0] + sA[1] + sA[2] + sA[3];
    bsB[blk] = sB[0] + sB[1] + sB[2] + sB[3];
  }
}

// stage B: single wave exclusive-scans the block sums in place (nb=79).
// All shfls all-lane-active (chunks padded with 0).
__global__ __launch_bounds__(64) void k_bscan(int* __restrict__ bsA, int* __restrict__ bsB,
                                              int nb) {
  int lane = threadIdx.x;
  for (int arr = 0; arr < 2; ++arr) {
    int* bs = arr ? bsB : bsA;
    int carry = 0;
    for (int base = 0; base < nb; base += 64) {
      int idx = base + lane;
      int v = (idx < nb) ? bs[idx] : 0;
      int s = v;
#pragma unroll
      for (int off = 1; off < 64; off <<= 1) {
        int x = __shfl_up(s, off, 64);
        if (lane >= off) s += x;
      }
      if (idx < nb) bs[idx] = carry + s - v;  // exclusive
      carry += __shfl(s, 63, 64);             // all lanes active: safe
    }
  }
}

// stage C: re-scan each 256-chunk and add the block offset -> row & cur
__global__ __launch_bounds__(256) void k_scan_apply(
    const int* __restrict__ dA, const int* __restrict__ dB, const int* __restrict__ bsA,
    const int* __restrict__ bsB, int* __restrict__ rowA, int* __restrict__ curA,
    int* __restrict__ rowB, int* __restrict__ curB) {
  __shared__ int ws[4];
  int blk = blockIdx.x, t = threadIdx.x;
  int wid = t >> 6, lane = t & 63;
  int i = blk * 256 + t;
  for (int arr = 0; arr < 2; ++arr) {
    const int* deg = arr ? dB : dA;
    const int* bs = arr ? bsB : bsA;
    int* row = arr ? rowB : rowA;
    int* cur = arr ? curB : curA;
    int v = (i < N) ? deg[i] : 0;
    int s = v;
#pragma unroll
    for (int off = 1; off < 64; off <<= 1) {
      int x = __shfl_up(s, off, 64);
      if (lane >= off) s += x;
    }
    if (lane == 63) ws[wid] = s;
    __syncthreads();
    int wexcl = 0;
    for (int k = 0; k < wid; ++k) wexcl += ws[k];  // wid uniform per wave
    int r = bs[blk] + wexcl + s - v;
    if (i < N) {
      row[i] = r;
      cur[i] = r;
    }
    __syncthreads();  // ws reused next pass
  }
}

__global__ void k_scatter(const int* __restrict__ ei, int* __restrict__ cur_dst,
                          int* __restrict__ cur_src, int* __restrict__ eid_dst,
                          int* __restrict__ esrc_dst, int* __restrict__ esrc_srt,
                          int* __restrict__ edst_srt) {
  int e = blockIdx.x * blockDim.x + threadIdx.x;
  if (e >= E) return;
  int s = ei[e], d = ei[E + e];
  int ps = atomicAdd(&cur_src[s], 1);
  esrc_srt[ps] = s;
  edst_srt[ps] = d;
  int pd = atomicAdd(&cur_dst[d], 1);
  eid_dst[pd] = e;
  esrc_dst[pd] = s;
}

__global__ void k_loop_attr(const int* __restrict__ row_dst, const int* __restrict__ deg_dst,
                            const int* __restrict__ eid_dst, const float* __restrict__ ea,
                            float* __restrict__ la) {
  int n = blockIdx.x * blockDim.x + threadIdx.x;
  if (n >= N) return;
  int beg = row_dst[n], cnt = deg_dst[n];
  float s[EDIM] = {0.f, 0.f, 0.f, 0.f, 0.f};
  for (int j = 0; j < cnt; ++j) {
    int e = eid_dst[beg + j];
#pragma unroll
    for (int k = 0; k < EDIM; ++k) s[k] += ea[(size_t)e * EDIM + k];
  }
  float inv = 1.f / fmaxf((float)cnt, 1.f);
#pragma unroll
  for (int k = 0; k < EDIM; ++k) la[n * EDIM + k] = s[k] * inv;
}

// v14 occupancy-split xl/xr GEMM (r22-proven, -75 µs): 64 weights/thread,
// block b<1250 -> xl (Wl), b>=1250 -> xr (Wr); block-uniform branch.
__global__ __launch_bounds__(256) void k_xlxr(const float* __restrict__ h,
                                              const float* __restrict__ Wl,
                                              const float* __restrict__ bl,
                                              const float* __restrict__ Wr,
                                              const float* __restrict__ br,
                                              float* __restrict__ xl, float* __restrict__ xr) {
  constexpr int NB = 16;
  __shared__ float hs[NB][HID];
  int half = (blockIdx.x >= XBLK) ? 1 : 0;  // block-uniform
  int blk = blockIdx.x - half * XBLK;
  const float* W = half ? Wr : Wl;
  const float* bias = half ? br : bl;
  float* outp = half ? xr : xl;
  int n0 = blk * NB;  // grid exact: all rows in-bounds
  for (int idx = threadIdx.x; idx < NB * HID; idx += 256) {
    int r = idx >> 6, c = idx & 63;
    hs[r][c] = h[(n0 + r) * HID + c];
  }
  __syncthreads();
  int t = threadIdx.x;
  float wv[HID];
#pragma unroll
  for (int k = 0; k < HID; ++k) wv[k] = W[k * HH + t];
  float bv = bias[t];
#pragma unroll 4
  for (int r = 0; r < NB; ++r) {
    float acc = bv;
#pragma unroll
    for (int k = 0; k < HID; ++k) acc += hs[r][k] * wv[k];
    outp[(size_t)(n0 + r) * HH + t] = acc;
  }
}

// per-node GATv2, fused ONLINE softmax, single xl gather, INDEX PREFETCH.
// r22-exact (r23's 2-stage value prefetch reverted: bundled A/B showed it
// offset the k_uv gain — +12 VGPR for no latency win at 80K-wave TLP).
// SAFETY INVARIANT: no data-dependent __shfl. Edge indices loaded directly
// at group-uniform addresses; next iteration's indices prefetched (bounds-
// guarded with valid dummy la[n]). Only shfls: within-group reduce (o<16,
// group-uniform activity) and all-lane end merges.
__global__ __launch_bounds__(256) void k_gat(
    const float* __restrict__ xl, const float* __restrict__ xr, const float* __restrict__ ea,
    const float* __restrict__ la, const int* __restrict__ row_dst,
    const int* __restrict__ deg_dst, const int* __restrict__ eid_dst,
    const int* __restrict__ esrc_dst, const float* __restrict__ We,
    const float* __restrict__ att, const float* __restrict__ biasL,
    const float* __restrict__ lng, const float* __restrict__ lnb, float* __restrict__ h) {
  __shared__ float heads[HEADS][HID];
  int n = blockIdx.x;
  int w = threadIdx.x >> 6, lane = threadIdx.x & 63;
  int g = lane >> 4, q = lane & 15, c4 = q * 4;
  float4 xr4 = *(const float4*)(xr + (size_t)n * HH + w * HID + c4);
  float4 att4 = *(const float4*)(att + w * HID + c4);
  float4 we4[EDIM];
#pragma unroll
  for (int k = 0; k < EDIM; ++k) we4[k] = *(const float4*)(We + k * HH + w * HID + c4);
  int beg = row_dst[n], cnt = deg_dst[n];
  int tot = cnt + 1;  // + self loop (idx 0)
  float mg = -INFINITY, sg = 0.f;
  float ax = 0.f, ay = 0.f, az = 0.f, aw2 = 0.f;
  // prefetch iteration 0's indices (group-uniform, always-valid addresses)
  int srcn_p;
  const float* eap_p;
  if (g == 0 || g >= tot) {
    srcn_p = n;
    eap_p = la + (size_t)n * EDIM;
  } else {
    int pos = beg + g - 1;
    srcn_p = esrc_dst[pos];
    eap_p = ea + (size_t)eid_dst[pos] * EDIM;
  }
  for (int j = 0; j * 4 < tot; ++j) {
    int idx = j * 4 + g;  // uniform within each 16-lane group
    int srcn = srcn_p;
    const float* eap = eap_p;
    int idx2 = idx + 4;
    if (idx2 >= tot) {
      srcn_p = n;
      eap_p = la + (size_t)n * EDIM;
    } else {
      int pos = beg + idx2 - 1;
      srcn_p = esrc_dst[pos];
      eap_p = ea + (size_t)eid_dst[pos] * EDIM;
    }
    if (idx < tot) {  // group-uniform predicate
      float4 ep;
      ep.x = ep.y = ep.z = ep.w = 0.f;
#pragma unroll
      for (int k = 0; k < EDIM; ++k) {
        float ev = eap[k];
        ep.x += ev * we4[k].x;
        ep.y += ev * we4[k].y;
        ep.z += ev * we4[k].z;
        ep.w += ev * we4[k].w;
      }
      float4 xl4 = *(const float4*)(xl + (size_t)srcn * HH + w * HID + c4);
      float v0 = xl4.x + xr4.x + ep.x;
      float v1 = xl4.y + xr4.y + ep.y;
      float v2 = xl4.z + xr4.z + ep.z;
      float v3 = xl4.w + xr4.w + ep.w;
      v0 = v0 > 0.f ? v0 : 0.2f * v0;
      v1 = v1 > 0.f ? v1 : 0.2f * v1;
      v2 = v2 > 0.f ? v2 : 0.2f * v2;
      v3 = v3 > 0.f ? v3 : 0.2f * v3;
      float dot = v0 * att4.x + v1 * att4.y + v2 * att4.z + v3 * att4.w;
      // within-group reduce: o<16 stays inside the fully-active group
#pragma unroll
      for (int o = 1; o < 16; o <<= 1) dot += __shfl_xor(dot, o, 64);
      // per-group online softmax update (register-only)
      float nm = fmaxf(mg, dot);
      float sc = __expf(mg - nm);  // first iter: exp(-inf)=0
      float pp = __expf(dot - nm);
      sg = sg * sc + pp;
      ax = ax * sc + pp * xl4.x;
      ay = ay * sc + pp * xl4.y;
      az = az * sc + pp * xl4.z;
      aw2 = aw2 * sc + pp * xl4.w;
      mg = nm;
    }
  }
  // merge the 4 group states (all 64 lanes active; pure register shfls)
  float mm = fmaxf(mg, __shfl_xor(mg, 16, 64));
  mm = fmaxf(mm, __shfl_xor(mm, 32, 64));
  float scale = __expf(mg - mm);  // never-active groups: exp(-inf)=0
  float st = sg * scale;
  st += __shfl_xor(st, 16, 64);
  st += __shfl_xor(st, 32, 64);
  ax *= scale; ax += __shfl_xor(ax, 16, 64); ax += __shfl_xor(ax, 32, 64);
  ay *= scale; ay += __shfl_xor(ay, 16, 64); ay += __shfl_xor(ay, 32, 64);
  az *= scale; az += __shfl_xor(az, 16, 64); az += __shfl_xor(az, 32, 64);
  aw2 *= scale; aw2 += __shfl_xor(aw2, 16, 64); aw2 += __shfl_xor(aw2, 32, 64);
  float inv = 1.f / (st + 1e-16f);
  if (g == 0) {
    heads[w][c4 + 0] = ax * inv;
    heads[w][c4 + 1] = ay * inv;
    heads[w][c4 + 2] = az * inv;
    heads[w][c4 + 3] = aw2 * inv;
  }
  __syncthreads();
  if (w == 0) {
    float hv = (heads[0][lane] + heads[1][lane] + heads[2][lane] + heads[3][lane]) * 0.25f +
               biasL[lane];
    hv = fmaxf(hv, 0.f);
    float v = hv + h[n * HID + lane];
    float mu = wredsum(v) * (1.f / 64.f);
    float d = v - mu;
    float var = wredsum(d * d) * (1.f / 64.f);
    h[n * HID + lane] = d * rsqrtf(var + 1e-5f) * lng[lane] + lnb[lane];
  }
}

// v15: k_uv occupancy-split (same transform as k_xlxr v14): block b<1250
// computes u (W1 top half + b1), b>=1250 computes v (W1 bottom half, no
// bias). 64 weights/thread, block-uniform branch, grid exact (N/16=1250).
__global__ __launch_bounds__(256) void k_uv(const float* __restrict__ h,
                                            const float* __restrict__ W1,
                                            const float* __restrict__ b1,
                                            float* __restrict__ u, float* __restrict__ v) {
  constexpr int NB = 16;
  __shared__ float hs[NB][HID];
  int half = (blockIdx.x >= XBLK) ? 1 : 0;  // block-uniform
  int blk = blockIdx.x - half * XBLK;
  int n0 = blk * NB;
  for (int idx = threadIdx.x; idx < NB * HID; idx += 256) {
    int r = idx >> 6, c = idx & 63;
    hs[r][c] = h[(n0 + r) * HID + c];
  }
  __syncthreads();
  int j = threadIdx.x & 63, q = threadIdx.x >> 6;
  const float* W = W1 + (half ? (size_t)HID * HID : 0);  // wb[k]=W1[(HID+k)*HID+j]
  float* outp = half ? v : u;
  float wv[HID];
#pragma unroll
  for (int k = 0; k < HID; ++k) wv[k] = W[k * HID + j];
  float bv = half ? 0.f : b1[j];
  for (int r = q; r < NB; r += 4) {
    float acc = bv;
#pragma unroll
    for (int k = 0; k < HID; ++k) acc += hs[r][k] * wv[k];
    outp[(size_t)(n0 + r) * HID + j] = acc;
  }
}

// r16-exact k_edge (best of 5 attempts at 67 µs): 4 waves/block, 32
// edges/wave. lane = output feature; W2/W2g columns per lane (compiler
// keeps them L1-hot; residency-forcing variants all regressed).
// Activations via wave-uniform broadcast ds_read_b128; coalesced stores.
__global__ __launch_bounds__(256) void k_edge(const float* __restrict__ u,
                                              const float* __restrict__ v,
                                              const int* __restrict__ esrc_srt,
                                              const int* __restrict__ edst_srt,
                                              const float* __restrict__ W2,
                                              const float* __restrict__ b2,
                                              const float* __restrict__ W2g,
                                              const float* __restrict__ bg2,
                                              float* __restrict__ gated) {
  __shared__ float T[4][32 * 68];
  int w = threadIdx.x >> 6, lane = threadIdx.x & 63;
  float* Tw = T[w];
  int p0 = blockIdx.x * 128 + w * 32;  // E % 128 == 0
  float w2c[HID], wgc[HID];
#pragma unroll
  for (int k = 0; k < HID; ++k) {
    w2c[k] = W2[k * HID + lane];   // coalesced: lane j gets column j
    wgc[k] = W2g[k * HID + lane];
  }
  float b2v = b2[lane], bgv = bg2[lane];
  int sv = esrc_srt[p0 + (lane & 31)];
  int dv = edst_srt[p0 + (lane & 31)];
  // phase A: coalesced activation-row gathers into this wave's LDS tile
  for (int i = 0; i < 32; ++i) {
    int si = __shfl(sv, i, 64), di = __shfl(dv, i, 64);
    Tw[i * 68 + lane] = fmaxf(u[(size_t)si * HID + lane] + v[(size_t)di * HID + lane], 0.f);
  }
  __syncthreads();
  // phase B: per edge, uniform-broadcast LDS reads feed dual register GEMV
#pragma unroll 2
  for (int i = 0; i < 32; ++i) {
    float it0 = b2v, gt0 = bgv, it1 = 0.f, gt1 = 0.f;
#pragma unroll
    for (int k4 = 0; k4 < 16; ++k4) {
      float4 a = *(const float4*)&Tw[i * 68 + k4 * 4];  // uniform addr -> broadcast
      it0 += a.x * w2c[k4 * 4 + 0];
      gt0 += a.x * wgc[k4 * 4 + 0];
      it1 += a.y * w2c[k4 * 4 + 1];
      gt1 += a.y * wgc[k4 * 4 + 1];
      it0 += a.z * w2c[k4 * 4 + 2];
      gt0 += a.z * wgc[k4 * 4 + 2];
      it1 += a.w * w2c[k4 * 4 + 3];
      gt1 += a.w * wgc[k4 * 4 + 3];
    }
    float it = it0 + it1, gt = gt0 + gt1;
    gated[(size_t)(p0 + i) * HID + lane] = it / (1.f + __expf(-gt));
  }
}

__global__ void k_pool(const float* __restrict__ h, const float* __restrict__ gated,
                       const int* __restrict__ row_src, const int* __restrict__ deg_src,
                       const float* __restrict__ g, const float* __restrict__ b,
                       float* __restrict__ out) {
  int n = blockIdx.x * 4 + (threadIdx.x >> 6);
  int lane = threadIdx.x & 63;
  if (n >= N) return;
  int beg = row_src[n], cnt = deg_src[n];
  float acc = 0.f;
  for (int i = 0; i < cnt; ++i) acc += gated[(size_t)(beg + i) * HID + lane];
  float v = h[n * HID + lane] + acc / fmaxf((float)cnt, 1.f);
  float mu = wredsum(v) * (1.f / 64.f);
  float d = v - mu;
  float var = wredsum(d * d) * (1.f / 64.f);
  out[n * HID + lane] = d * rsqrtf(var + 1e-5f) * g[lane] + b[lane];
}

extern "C" void kernel_launch(void* const* d_in, const int* in_sizes, int n_in, void* d_out,
                              int out_size, void* d_ws, size_t ws_size, hipStream_t stream) {
  const float* x = (const float*)d_in[0];
  const int* ei = (const int*)d_in[1];
  const float* eattr = (const float*)d_in[2];
  const float* ctx = (const float*)d_in[3];
  const int* batch = (const int*)d_in[4];
  const int* role = (const int*)d_in[5];
  const int* side = (const int*)d_in[6];
  const int* form = (const int*)d_in[7];
  const int* alig = (const int*)d_in[8];
  const float* frame_t = (const float*)d_in[9];
  const float* emb_W = (const float*)d_in[10];
  const float* emb_b = (const float*)d_in[11];
  const float* role_tab = (const float*)d_in[12];
  const float* side_tab = (const float*)d_in[13];
  const float* ctx_W = (const float*)d_in[14];
  const float* ctx_b = (const float*)d_in[15];
  const float* form_tab = (const float*)d_in[16];
  const float* align_tab = (const float*)d_in[17];
  const float* temp_tab = (const float*)d_in[18];
  const float* gat_Wl = (const float*)d_in[19];
  const float* gat_bl = (const float*)d_in[20];
  const float* gat_Wr = (const float*)d_in[21];
  const float* gat_br = (const float*)d_in[22];
  const float* gat_We = (const float*)d_in[23];
  const float* gat_att = (const float*)d_in[24];
  const float* gat_bias = (const float*)d_in[25];
  const float* ln_g = (const float*)d_in[26];
  const float* ln_b = (const float*)d_in[27];
  const float* sp_W1 = (const float*)d_in[28];
  const float* sp_b1 = (const float*)d_in[29];
  const float* sp_W2 = (const float*)d_in[30];
  const float* sp_b2 = (const float*)d_in[31];
  const float* sp_Wg = (const float*)d_in[32];
  const float* sp_bg = (const float*)d_in[33];
  const float* fn_g = (const float*)d_in[34];
  const float* fn_b = (const float*)d_in[35];
  float* out = (float*)d_out;

  char* wp = (char*)d_ws;
  auto alloc = [&](size_t bytes) {
    void* p = (void*)wp;
    wp += (bytes + 255) & ~(size_t)255;
    return p;
  };
  float* h = (float*)alloc((size_t)N * HID * 4);
  float* xl = (float*)alloc((size_t)N * HH * 4);  // + xr below = 41 MB, reused as gated[E][64]
  float* xr = (float*)alloc((size_t)N * HH * 4);
  float* la = (float*)alloc((size_t)N * EDIM * 4);
  float* u = (float*)alloc((size_t)N * HID * 4);
  float* v = (float*)alloc((size_t)N * HID * 4);
  float* W2g = (float*)alloc((size_t)HID * HID * 4);
  float* bg2 = (float*)alloc((size_t)HID * 4);
  int* deg_dst = (int*)alloc((size_t)N * 4);
  int* deg_src = (int*)alloc((size_t)N * 4);
  int* row_dst = (int*)alloc((size_t)N * 4);
  int* row_src = (int*)alloc((size_t)N * 4);
  int* cur_dst = (int*)alloc((size_t)N * 4);
  int* cur_src = (int*)alloc((size_t)N * 4);
  int* eid_dst = (int*)alloc((size_t)E * 4);
  int* esrc_dst = (int*)alloc((size_t)E * 4);
  int* esrc_srt = (int*)alloc((size_t)E * 4);
  int* edst_srt = (int*)alloc((size_t)E * 4);
  int* bsA = (int*)alloc((size_t)SNB * 4);
  int* bsB = (int*)alloc((size_t)SNB * 4);
  float* gated = xl;  // [E][64] = 41 MB, spans xl+xr (both dead by then)

  hipMemsetAsync(deg_dst, 0, (size_t)N * 4, stream);
  hipMemsetAsync(deg_src, 0, (size_t)N * 4, stream);

  k_node_init<<<(N * HID + 255) / 256, 256, 0, stream>>>(
      x, emb_W, emb_b, role, role_tab, side, side_tab, frame_t, temp_tab, batch, ctx, ctx_W,
      ctx_b, form_tab, align_tab, form, alig, h);
  k_count<<<(E + 255) / 256, 256, 0, stream>>>(ei, deg_dst, deg_src);
  k_fuse<<<16, 256, 0, stream>>>(sp_W2, sp_Wg, sp_b2, sp_bg, W2g, bg2);
  k_bsum<<<SNB, 256, 0, stream>>>(deg_dst, deg_src, bsA, bsB);
  k_bscan<<<1, 64, 0, stream>>>(bsA, bsB, SNB);
  k_scan_apply<<<SNB, 256, 0, stream>>>(deg_dst, deg_src, bsA, bsB, row_dst, cur_dst, row_src,
                                        cur_src);
  k_scatter<<<(E + 255) / 256, 256, 0, stream>>>(ei, cur_dst, cur_src, eid_dst, esrc_dst,
                                                 esrc_srt, edst_srt);
  k_loop_attr<<<(N + 255) / 256, 256, 0, stream>>>(row_dst, deg_dst, eid_dst, eattr, la);

  for (int i = 0; i < NL; ++i) {
    k_xlxr<<<2 * XBLK, 256, 0, stream>>>(h, gat_Wl + (size_t)i * HID * HH, gat_bl + i * HH,
                                         gat_Wr + (size_t)i * HID * HH, gat_br + i * HH, xl, xr);
    k_gat<<<N, 256, 0, stream>>>(xl, xr, eattr, la, row_dst, deg_dst, eid_dst, esrc_dst,
                                 gat_We + (size_t)i * EDIM * HH, gat_att + i * HH,
                                 gat_bias + i * HID, ln_g + i * HID, ln_b + i * HID, h);
  }

  k_uv<<<2 * XBLK, 256, 0, stream>>>(h, sp_W1, sp_b1, u, v);
  k_edge<<<E / 128, 256, 0, stream>>>(u, v, esrc_srt, edst_srt, sp_W2, sp_b2, W2g, bg2, gated);
  k_pool<<<(N + 3) / 4, 256, 0, stream>>>(h, gated, row_src, deg_src, fn_g, fn_b, out);
}

// Round 25
// 520.719 us; speedup vs baseline: 1.0231x; 1.0146x over previous
//
#include <hip/hip_runtime.h>
#include <math.h>

constexpr int N = 20000, E = 160000, Bb = 1000;
constexpr int DIN = 7, HID = 64, HEADS = 4, CTXD = 3, EDIM = 5, NL = 4;
constexpr int HH = HEADS * HID; // 256
constexpr int SNB = (N + 255) / 256;  // 79 scan blocks
constexpr int XBLK = N / 16;          // 1250 node-tile blocks

__device__ __forceinline__ float wredsum(float v) {
#pragma unroll
  for (int o = 32; o; o >>= 1) v += __shfl_xor(v, o, 64);
  return v;
}

__device__ __forceinline__ int wredsumi(int v) {
#pragma unroll
  for (int o = 32; o; o >>= 1) v += __shfl_xor(v, o, 64);
  return v;
}

// node init (ctx MLP fused) + FOLDED-IN k_count (threads t<E count one edge)
// and k_fuse (t<HID^2 compute one W2g entry; t<HID one bg2 entry). All three
// are data-independent; atomics order-independent; deg memsets precede this
// kernel on the same stream, and all consumers launch after it.
__global__ void k_node_init(const float* __restrict__ x, const float* __restrict__ emb_W,
                            const float* __restrict__ emb_b, const int* __restrict__ role,
                            const float* __restrict__ role_tab, const int* __restrict__ side,
                            const float* __restrict__ side_tab, const float* __restrict__ frame_t,
                            const float* __restrict__ temp_tab, const int* __restrict__ batch,
                            const float* __restrict__ ctx, const float* __restrict__ ctx_W,
                            const float* __restrict__ ctx_b, const float* __restrict__ form_tab,
                            const float* __restrict__ align_tab, const int* __restrict__ form,
                            const int* __restrict__ alig, float* __restrict__ h,
                            const int* __restrict__ ei, int* __restrict__ deg_dst,
                            int* __restrict__ deg_src, const float* __restrict__ W2,
                            const float* __restrict__ Wg, const float* __restrict__ b2,
                            const float* __restrict__ bg, float* __restrict__ W2g,
                            float* __restrict__ bg2) {
  int t = blockIdx.x * blockDim.x + threadIdx.x;
  if (t >= N * HID) return;
  // folded k_count
  if (t < E) {
    atomicAdd(&deg_src[ei[t]], 1);
    atomicAdd(&deg_dst[ei[E + t]], 1);
  }
  // folded k_fuse
  if (t < HID * HID) {
    int i = t >> 6, j2 = t & 63;
    float a = 0.f;
#pragma unroll
    for (int k = 0; k < HID; ++k) a += W2[i * HID + k] * Wg[k * HID + j2];
    W2g[t] = a;
  }
  if (t < HID) {
    float a = bg[t];
#pragma unroll
    for (int k = 0; k < HID; ++k) a += b2[k] * Wg[k * HID + t];
    bg2[t] = a;
  }
  // node init
  int n = t >> 6, j = t & 63;
  float a = emb_b[j];
#pragma unroll
  for (int k = 0; k < DIN; ++k) a += x[n * DIN + k] * emb_W[k * HID + j];
  a = fmaxf(a, 0.f);
  a += role_tab[role[n] * HID + j];
  if (j < 32) a += side_tab[side[n] * 32 + j];
  int ti = (int)(frame_t[0] * 99.f);
  ti = ti < 0 ? 0 : (ti > 99 ? 99 : ti);
  a += temp_tab[ti * HID + j];
  int b = batch[n];
  float c = ctx_b[j];
#pragma unroll
  for (int k = 0; k < CTXD; ++k) c += ctx[b * CTXD + k] * ctx_W[k * HID + j];
  c = fmaxf(c, 0.f);
  c += form_tab[form[b] * HID + j] + align_tab[alig[b] * HID + j];
  h[t] = a + c;
}

// parallel 2-level scan, stage A: per-block sums of both deg arrays
__global__ __launch_bounds__(256) void k_bsum(const int* __restrict__ dA,
                                              const int* __restrict__ dB,
                                              int* __restrict__ bsA, int* __restrict__ bsB) {
  __shared__ int sA[4], sB[4];
  int blk = blockIdx.x, t = threadIdx.x;
  int wid = t >> 6, lane = t & 63;
  int i = blk * 256 + t;
  int vA = (i < N) ? dA[i] : 0;
  int vB = (i < N) ? dB[i] : 0;
  int rA = wredsumi(vA), rB = wredsumi(vB);
  if (lane == 0) {
    sA[wid] = rA;
    sB[wid] = rB;
  }
  __syncthreads();
  if (t == 0) {
    bsA[blk] = sA[0] + sA[1] + sA[2] + sA[3];
    bsB[blk] = sB[0] + sB[1] + sB[2] + sB[3];
  }
}

// stage B: single wave exclusive-scans the block sums in place (nb=79).
__global__ __launch_bounds__(64) void k_bscan(int* __restrict__ bsA, int* __restrict__ bsB,
                                              int nb) {
  int lane = threadIdx.x;
  for (int arr = 0; arr < 2; ++arr) {
    int* bs = arr ? bsB : bsA;
    int carry = 0;
    for (int base = 0; base < nb; base += 64) {
      int idx = base + lane;
      int v = (idx < nb) ? bs[idx] : 0;
      int s = v;
#pragma unroll
      for (int off = 1; off < 64; off <<= 1) {
        int x = __shfl_up(s, off, 64);
        if (lane >= off) s += x;
      }
      if (idx < nb) bs[idx] = carry + s - v;  // exclusive
      carry += __shfl(s, 63, 64);             // all lanes active: safe
    }
  }
}

// stage C: re-scan each 256-chunk and add the block offset -> row & cur
__global__ __launch_bounds__(256) void k_scan_apply(
    const int* __restrict__ dA, const int* __restrict__ dB, const int* __restrict__ bsA,
    const int* __restrict__ bsB, int* __restrict__ rowA, int* __restrict__ curA,
    int* __restrict__ rowB, int* __restrict__ curB) {
  __shared__ int ws[4];
  int blk = blockIdx.x, t = threadIdx.x;
  int wid = t >> 6, lane = t & 63;
  int i = blk * 256 + t;
  for (int arr = 0; arr < 2; ++arr) {
    const int* deg = arr ? dB : dA;
    const int* bs = arr ? bsB : bsA;
    int* row = arr ? rowB : rowA;
    int* cur = arr ? curB : curA;
    int v = (i < N) ? deg[i] : 0;
    int s = v;
#pragma unroll
    for (int off = 1; off < 64; off <<= 1) {
      int x = __shfl_up(s, off, 64);
      if (lane >= off) s += x;
    }
    if (lane == 63) ws[wid] = s;
    __syncthreads();
    int wexcl = 0;
    for (int k = 0; k < wid; ++k) wexcl += ws[k];  // wid uniform per wave
    int r = bs[blk] + wexcl + s - v;
    if (i < N) {
      row[i] = r;
      cur[i] = r;
    }
    __syncthreads();  // ws reused next pass
  }
}

__global__ void k_scatter(const int* __restrict__ ei, int* __restrict__ cur_dst,
                          int* __restrict__ cur_src, int* __restrict__ eid_dst,
                          int* __restrict__ esrc_dst, int* __restrict__ esrc_srt,
                          int* __restrict__ edst_srt) {
  int e = blockIdx.x * blockDim.x + threadIdx.x;
  if (e >= E) return;
  int s = ei[e], d = ei[E + e];
  int ps = atomicAdd(&cur_src[s], 1);
  esrc_srt[ps] = s;
  edst_srt[ps] = d;
  int pd = atomicAdd(&cur_dst[d], 1);
  eid_dst[pd] = e;
  esrc_dst[pd] = s;
}

__global__ void k_loop_attr(const int* __restrict__ row_dst, const int* __restrict__ deg_dst,
                            const int* __restrict__ eid_dst, const float* __restrict__ ea,
                            float* __restrict__ la) {
  int n = blockIdx.x * blockDim.x + threadIdx.x;
  if (n >= N) return;
  int beg = row_dst[n], cnt = deg_dst[n];
  float s[EDIM] = {0.f, 0.f, 0.f, 0.f, 0.f};
  for (int j = 0; j < cnt; ++j) {
    int e = eid_dst[beg + j];
#pragma unroll
    for (int k = 0; k < EDIM; ++k) s[k] += ea[(size_t)e * EDIM + k];
  }
  float inv = 1.f / fmaxf((float)cnt, 1.f);
#pragma unroll
  for (int k = 0; k < EDIM; ++k) la[n * EDIM + k] = s[k] * inv;
}

// v14 occupancy-split xl/xr GEMM (r22-proven, -75 µs): 64 weights/thread,
// block b<1250 -> xl (Wl), b>=1250 -> xr (Wr); block-uniform branch.
__global__ __launch_bounds__(256) void k_xlxr(const float* __restrict__ h,
                                              const float* __restrict__ Wl,
                                              const float* __restrict__ bl,
                                              const float* __restrict__ Wr,
                                              const float* __restrict__ br,
                                              float* __restrict__ xl, float* __restrict__ xr) {
  constexpr int NB = 16;
  __shared__ float hs[NB][HID];
  int half = (blockIdx.x >= XBLK) ? 1 : 0;  // block-uniform
  int blk = blockIdx.x - half * XBLK;
  const float* W = half ? Wr : Wl;
  const float* bias = half ? br : bl;
  float* outp = half ? xr : xl;
  int n0 = blk * NB;  // grid exact: all rows in-bounds
  for (int idx = threadIdx.x; idx < NB * HID; idx += 256) {
    int r = idx >> 6, c = idx & 63;
    hs[r][c] = h[(n0 + r) * HID + c];
  }
  __syncthreads();
  int t = threadIdx.x;
  float wv[HID];
#pragma unroll
  for (int k = 0; k < HID; ++k) wv[k] = W[k * HH + t];
  float bv = bias[t];
#pragma unroll 4
  for (int r = 0; r < NB; ++r) {
    float acc = bv;
#pragma unroll
    for (int k = 0; k < HID; ++k) acc += hs[r][k] * wv[k];
    outp[(size_t)(n0 + r) * HH + t] = acc;
  }
}

// per-node GATv2, fused ONLINE softmax, single xl gather, INDEX PREFETCH.
// r22-exact (best-measured variant). SAFETY INVARIANT: no data-dependent
// __shfl; group-uniform index loads; within-group o<16 reduces + all-lane
// merges only.
__global__ __launch_bounds__(256) void k_gat(
    const float* __restrict__ xl, const float* __restrict__ xr, const float* __restrict__ ea,
    const float* __restrict__ la, const int* __restrict__ row_dst,
    const int* __restrict__ deg_dst, const int* __restrict__ eid_dst,
    const int* __restrict__ esrc_dst, const float* __restrict__ We,
    const float* __restrict__ att, const float* __restrict__ biasL,
    const float* __restrict__ lng, const float* __restrict__ lnb, float* __restrict__ h) {
  __shared__ float heads[HEADS][HID];
  int n = blockIdx.x;
  int w = threadIdx.x >> 6, lane = threadIdx.x & 63;
  int g = lane >> 4, q = lane & 15, c4 = q * 4;
  float4 xr4 = *(const float4*)(xr + (size_t)n * HH + w * HID + c4);
  float4 att4 = *(const float4*)(att + w * HID + c4);
  float4 we4[EDIM];
#pragma unroll
  for (int k = 0; k < EDIM; ++k) we4[k] = *(const float4*)(We + k * HH + w * HID + c4);
  int beg = row_dst[n], cnt = deg_dst[n];
  int tot = cnt + 1;  // + self loop (idx 0)
  float mg = -INFINITY, sg = 0.f;
  float ax = 0.f, ay = 0.f, az = 0.f, aw2 = 0.f;
  int srcn_p;
  const float* eap_p;
  if (g == 0 || g >= tot) {
    srcn_p = n;
    eap_p = la + (size_t)n * EDIM;
  } else {
    int pos = beg + g - 1;
    srcn_p = esrc_dst[pos];
    eap_p = ea + (size_t)eid_dst[pos] * EDIM;
  }
  for (int j = 0; j * 4 < tot; ++j) {
    int idx = j * 4 + g;  // uniform within each 16-lane group
    int srcn = srcn_p;
    const float* eap = eap_p;
    int idx2 = idx + 4;
    if (idx2 >= tot) {
      srcn_p = n;
      eap_p = la + (size_t)n * EDIM;
    } else {
      int pos = beg + idx2 - 1;
      srcn_p = esrc_dst[pos];
      eap_p = ea + (size_t)eid_dst[pos] * EDIM;
    }
    if (idx < tot) {  // group-uniform predicate
      float4 ep;
      ep.x = ep.y = ep.z = ep.w = 0.f;
#pragma unroll
      for (int k = 0; k < EDIM; ++k) {
        float ev = eap[k];
        ep.x += ev * we4[k].x;
        ep.y += ev * we4[k].y;
        ep.z += ev * we4[k].z;
        ep.w += ev * we4[k].w;
      }
      float4 xl4 = *(const float4*)(xl + (size_t)srcn * HH + w * HID + c4);
      float v0 = xl4.x + xr4.x + ep.x;
      float v1 = xl4.y + xr4.y + ep.y;
      float v2 = xl4.z + xr4.z + ep.z;
      float v3 = xl4.w + xr4.w + ep.w;
      v0 = v0 > 0.f ? v0 : 0.2f * v0;
      v1 = v1 > 0.f ? v1 : 0.2f * v1;
      v2 = v2 > 0.f ? v2 : 0.2f * v2;
      v3 = v3 > 0.f ? v3 : 0.2f * v3;
      float dot = v0 * att4.x + v1 * att4.y + v2 * att4.z + v3 * att4.w;
#pragma unroll
      for (int o = 1; o < 16; o <<= 1) dot += __shfl_xor(dot, o, 64);
      float nm = fmaxf(mg, dot);
      float sc = __expf(mg - nm);  // first iter: exp(-inf)=0
      float pp = __expf(dot - nm);
      sg = sg * sc + pp;
      ax = ax * sc + pp * xl4.x;
      ay = ay * sc + pp * xl4.y;
      az = az * sc + pp * xl4.z;
      aw2 = aw2 * sc + pp * xl4.w;
      mg = nm;
    }
  }
  float mm = fmaxf(mg, __shfl_xor(mg, 16, 64));
  mm = fmaxf(mm, __shfl_xor(mm, 32, 64));
  float scale = __expf(mg - mm);  // never-active groups: exp(-inf)=0
  float st = sg * scale;
  st += __shfl_xor(st, 16, 64);
  st += __shfl_xor(st, 32, 64);
  ax *= scale; ax += __shfl_xor(ax, 16, 64); ax += __shfl_xor(ax, 32, 64);
  ay *= scale; ay += __shfl_xor(ay, 16, 64); ay += __shfl_xor(ay, 32, 64);
  az *= scale; az += __shfl_xor(az, 16, 64); az += __shfl_xor(az, 32, 64);
  aw2 *= scale; aw2 += __shfl_xor(aw2, 16, 64); aw2 += __shfl_xor(aw2, 32, 64);
  float inv = 1.f / (st + 1e-16f);
  if (g == 0) {
    heads[w][c4 + 0] = ax * inv;
    heads[w][c4 + 1] = ay * inv;
    heads[w][c4 + 2] = az * inv;
    heads[w][c4 + 3] = aw2 * inv;
  }
  __syncthreads();
  if (w == 0) {
    float hv = (heads[0][lane] + heads[1][lane] + heads[2][lane] + heads[3][lane]) * 0.25f +
               biasL[lane];
    hv = fmaxf(hv, 0.f);
    float v = hv + h[n * HID + lane];
    float mu = wredsum(v) * (1.f / 64.f);
    float d = v - mu;
    float var = wredsum(d * d) * (1.f / 64.f);
    h[n * HID + lane] = d * rsqrtf(var + 1e-5f) * lng[lane] + lnb[lane];
  }
}

// v15: k_uv occupancy-split: block b<1250 -> u (W1 top half + b1),
// b>=1250 -> v (W1 bottom half). 64 weights/thread, grid exact.
__global__ __launch_bounds__(256) void k_uv(const float* __restrict__ h,
                                            const float* __restrict__ W1,
                                            const float* __restrict__ b1,
                                            float* __restrict__ u, float* __restrict__ v) {
  constexpr int NB = 16;
  __shared__ float hs[NB][HID];
  int half = (blockIdx.x >= XBLK) ? 1 : 0;  // block-uniform
  int blk = blockIdx.x - half * XBLK;
  int n0 = blk * NB;
  for (int idx = threadIdx.x; idx < NB * HID; idx += 256) {
    int r = idx >> 6, c = idx & 63;
    hs[r][c] = h[(n0 + r) * HID + c];
  }
  __syncthreads();
  int j = threadIdx.x & 63, q = threadIdx.x >> 6;
  const float* W = W1 + (half ? (size_t)HID * HID : 0);
  float* outp = half ? v : u;
  float wv[HID];
#pragma unroll
  for (int k = 0; k < HID; ++k) wv[k] = W[k * HID + j];
  float bv = half ? 0.f : b1[j];
  for (int r = q; r < NB; r += 4) {
    float acc = bv;
#pragma unroll
    for (int k = 0; k < HID; ++k) acc += hs[r][k] * wv[k];
    outp[(size_t)(n0 + r) * HID + j] = acc;
  }
}

// r16-exact k_edge (best of 5 attempts at 67 µs): 4 waves/block, 32
// edges/wave; W2/W2g columns per lane; wave-uniform broadcast ds_read_b128.
__global__ __launch_bounds__(256) void k_edge(const float* __restrict__ u,
                                              const float* __restrict__ v,
                                              const int* __restrict__ esrc_srt,
                                              const int* __restrict__ edst_srt,
                                              const float* __restrict__ W2,
                                              const float* __restrict__ b2,
                                              const float* __restrict__ W2g,
                                              const float* __restrict__ bg2,
                                              float* __restrict__ gated) {
  __shared__ float T[4][32 * 68];
  int w = threadIdx.x >> 6, lane = threadIdx.x & 63;
  float* Tw = T[w];
  int p0 = blockIdx.x * 128 + w * 32;  // E % 128 == 0
  float w2c[HID], wgc[HID];
#pragma unroll
  for (int k = 0; k < HID; ++k) {
    w2c[k] = W2[k * HID + lane];
    wgc[k] = W2g[k * HID + lane];
  }
  float b2v = b2[lane], bgv = bg2[lane];
  int sv = esrc_srt[p0 + (lane & 31)];
  int dv = edst_srt[p0 + (lane & 31)];
  for (int i = 0; i < 32; ++i) {
    int si = __shfl(sv, i, 64), di = __shfl(dv, i, 64);
    Tw[i * 68 + lane] = fmaxf(u[(size_t)si * HID + lane] + v[(size_t)di * HID + lane], 0.f);
  }
  __syncthreads();
#pragma unroll 2
  for (int i = 0; i < 32; ++i) {
    float it0 = b2v, gt0 = bgv, it1 = 0.f, gt1 = 0.f;
#pragma unroll
    for (int k4 = 0; k4 < 16; ++k4) {
      float4 a = *(const float4*)&Tw[i * 68 + k4 * 4];
      it0 += a.x * w2c[k4 * 4 + 0];
      gt0 += a.x * wgc[k4 * 4 + 0];
      it1 += a.y * w2c[k4 * 4 + 1];
      gt1 += a.y * wgc[k4 * 4 + 1];
      it0 += a.z * w2c[k4 * 4 + 2];
      gt0 += a.z * wgc[k4 * 4 + 2];
      it1 += a.w * w2c[k4 * 4 + 3];
      gt1 += a.w * wgc[k4 * 4 + 3];
    }
    float it = it0 + it1, gt = gt0 + gt1;
    gated[(size_t)(p0 + i) * HID + lane] = it / (1.f + __expf(-gt));
  }
}

__global__ void k_pool(const float* __restrict__ h, const float* __restrict__ gated,
                       const int* __restrict__ row_src, const int* __restrict__ deg_src,
                       const float* __restrict__ g, const float* __restrict__ b,
                       float* __restrict__ out) {
  int n = blockIdx.x * 4 + (threadIdx.x >> 6);
  int lane = threadIdx.x & 63;
  if (n >= N) return;
  int beg = row_src[n], cnt = deg_src[n];
  float acc = 0.f;
  for (int i = 0; i < cnt; ++i) acc += gated[(size_t)(beg + i) * HID + lane];
  float v = h[n * HID + lane] + acc / fmaxf((float)cnt, 1.f);
  float mu = wredsum(v) * (1.f / 64.f);
  float d = v - mu;
  float var = wredsum(d * d) * (1.f / 64.f);
  out[n * HID + lane] = d * rsqrtf(var + 1e-5f) * g[lane] + b[lane];
}

extern "C" void kernel_launch(void* const* d_in, const int* in_sizes, int n_in, void* d_out,
                              int out_size, void* d_ws, size_t ws_size, hipStream_t stream) {
  const float* x = (const float*)d_in[0];
  const int* ei = (const int*)d_in[1];
  const float* eattr = (const float*)d_in[2];
  const float* ctx = (const float*)d_in[3];
  const int* batch = (const int*)d_in[4];
  const int* role = (const int*)d_in[5];
  const int* side = (const int*)d_in[6];
  const int* form = (const int*)d_in[7];
  const int* alig = (const int*)d_in[8];
  const float* frame_t = (const float*)d_in[9];
  const float* emb_W = (const float*)d_in[10];
  const float* emb_b = (const float*)d_in[11];
  const float* role_tab = (const float*)d_in[12];
  const float* side_tab = (const float*)d_in[13];
  const float* ctx_W = (const float*)d_in[14];
  const float* ctx_b = (const float*)d_in[15];
  const float* form_tab = (const float*)d_in[16];
  const float* align_tab = (const float*)d_in[17];
  const float* temp_tab = (const float*)d_in[18];
  const float* gat_Wl = (const float*)d_in[19];
  const float* gat_bl = (const float*)d_in[20];
  const float* gat_Wr = (const float*)d_in[21];
  const float* gat_br = (const float*)d_in[22];
  const float* gat_We = (const float*)d_in[23];
  const float* gat_att = (const float*)d_in[24];
  const float* gat_bias = (const float*)d_in[25];
  const float* ln_g = (const float*)d_in[26];
  const float* ln_b = (const float*)d_in[27];
  const float* sp_W1 = (const float*)d_in[28];
  const float* sp_b1 = (const float*)d_in[29];
  const float* sp_W2 = (const float*)d_in[30];
  const float* sp_b2 = (const float*)d_in[31];
  const float* sp_Wg = (const float*)d_in[32];
  const float* sp_bg = (const float*)d_in[33];
  const float* fn_g = (const float*)d_in[34];
  const float* fn_b = (const float*)d_in[35];
  float* out = (float*)d_out;

  char* wp = (char*)d_ws;
  auto alloc = [&](size_t bytes) {
    void* p = (void*)wp;
    wp += (bytes + 255) & ~(size_t)255;
    return p;
  };
  float* h = (float*)alloc((size_t)N * HID * 4);
  float* xl = (float*)alloc((size_t)N * HH * 4);  // + xr below = 41 MB, reused as gated[E][64]
  float* xr = (float*)alloc((size_t)N * HH * 4);
  float* la = (float*)alloc((size_t)N * EDIM * 4);
  float* u = (float*)alloc((size_t)N * HID * 4);
  float* v = (float*)alloc((size_t)N * HID * 4);
  float* W2g = (float*)alloc((size_t)HID * HID * 4);
  float* bg2 = (float*)alloc((size_t)HID * 4);
  int* deg_dst = (int*)alloc((size_t)N * 4);
  int* deg_src = (int*)alloc((size_t)N * 4);
  int* row_dst = (int*)alloc((size_t)N * 4);
  int* row_src = (int*)alloc((size_t)N * 4);
  int* cur_dst = (int*)alloc((size_t)N * 4);
  int* cur_src = (int*)alloc((size_t)N * 4);
  int* eid_dst = (int*)alloc((size_t)E * 4);
  int* esrc_dst = (int*)alloc((size_t)E * 4);
  int* esrc_srt = (int*)alloc((size_t)E * 4);
  int* edst_srt = (int*)alloc((size_t)E * 4);
  int* bsA = (int*)alloc((size_t)SNB * 4);
  int* bsB = (int*)alloc((size_t)SNB * 4);
  float* gated = xl;  // [E][64] = 41 MB, spans xl+xr (both dead by then)

  hipMemsetAsync(deg_dst, 0, (size_t)N * 4, stream);
  hipMemsetAsync(deg_src, 0, (size_t)N * 4, stream);

  k_node_init<<<(N * HID + 255) / 256, 256, 0, stream>>>(
      x, emb_W, emb_b, role, role_tab, side, side_tab, frame_t, temp_tab, batch, ctx, ctx_W,
      ctx_b, form_tab, align_tab, form, alig, h, ei, deg_dst, deg_src, sp_W2, sp_Wg, sp_b2,
      sp_bg, W2g, bg2);
  k_bsum<<<SNB, 256, 0, stream>>>(deg_dst, deg_src, bsA, bsB);
  k_bscan<<<1, 64, 0, stream>>>(bsA, bsB, SNB);
  k_scan_apply<<<SNB, 256, 0, stream>>>(deg_dst, deg_src, bsA, bsB, row_dst, cur_dst, row_src,
                                        cur_src);
  k_scatter<<<(E + 255) / 256, 256, 0, stream>>>(ei, cur_dst, cur_src, eid_dst, esrc_dst,
                                                 esrc_srt, edst_srt);
  k_loop_attr<<<(N + 255) / 256, 256, 0, stream>>>(row_dst, deg_dst, eid_dst, eattr, la);

  for (int i = 0; i < NL; ++i) {
    k_xlxr<<<2 * XBLK, 256, 0, stream>>>(h, gat_Wl + (size_t)i * HID * HH, gat_bl + i * HH,
                                         gat_Wr + (size_t)i * HID * HH, gat_br + i * HH, xl, xr);
    k_gat<<<N, 256, 0, stream>>>(xl, xr, eattr, la, row_dst, deg_dst, eid_dst, esrc_dst,
                                 gat_We + (size_t)i * EDIM * HH, gat_att + i * HH,
                                 gat_bias + i * HID, ln_g + i * HID, ln_b + i * HID, h);
  }

  k_uv<<<2 * XBLK, 256, 0, stream>>>(h, sp_W1, sp_b1, u, v);
  k_edge<<<E / 128, 256, 0, stream>>>(u, v, esrc_srt, edst_srt, sp_W2, sp_b2, W2g, bg2, gated);
  k_pool<<<(N + 3) / 4, 256, 0, stream>>>(h, gated, row_src, deg_src, fn_g, fn_b, out);
}